// Round 1
// baseline (711.042 us; speedup 1.0000x reference)
//
#include <hip/hip_runtime.h>
#include <cmath>

#define Bn 8
#define Tn 2048
#define Cn 1024
#define Kn 128

// ---------------------------------------------------------------------------
// Projection: out = x @ W, for W in {Wq, Wk, Wv} (grid.y selects which).
// Block: 256 threads computes a 128x128 output tile; C is chunked by 64.
// Each thread owns an 8x8 register tile. x chunk stored TRANSPOSED in LDS so
// the inner loop is pure float4 reads.
// ---------------------------------------------------------------------------
constexpr int PR  = 128;  // rows per block
constexpr int PCB = 64;   // C chunk

__global__ __launch_bounds__(256)
void proj_kernel(const float* __restrict__ x,
                 const float* __restrict__ Wq,
                 const float* __restrict__ Wk,
                 const float* __restrict__ Wv,
                 float* __restrict__ qo, float* __restrict__ ko, float* __restrict__ vo)
{
    const float* W = (blockIdx.y == 0) ? Wq : (blockIdx.y == 1) ? Wk : Wv;
    float* outp    = (blockIdx.y == 0) ? qo : (blockIdx.y == 1) ? ko : vo;
    const int row0 = blockIdx.x * PR;
    const int tid  = threadIdx.x;

    __shared__ float xs[PCB][PR + 4];    // transposed x chunk: xs[c][r]
    __shared__ float wsm[PCB][Kn + 4];   // W chunk: wsm[c][col]

    const int rg = tid >> 4;   // 0..15 -> rows rg*8 .. rg*8+7
    const int cg = tid & 15;   // 0..15 -> cols cg*8 .. cg*8+7

    float acc[8][8];
    #pragma unroll
    for (int i = 0; i < 8; ++i)
        #pragma unroll
        for (int j = 0; j < 8; ++j) acc[i][j] = 0.f;

    for (int c0 = 0; c0 < Cn; c0 += PCB) {
        __syncthreads();
        // Load x chunk (PR x PCB), store transposed. Coalesced global reads.
        #pragma unroll
        for (int it = 0; it < (PR * PCB / 4) / 256; ++it) {
            int i  = tid + it * 256;
            int r  = i >> 4;              // PCB/4 = 16 float4 per row
            int c4 = (i & 15) << 2;
            float4 xv = *(const float4*)(x + (size_t)(row0 + r) * Cn + c0 + c4);
            xs[c4 + 0][r] = xv.x;
            xs[c4 + 1][r] = xv.y;
            xs[c4 + 2][r] = xv.z;
            xs[c4 + 3][r] = xv.w;
        }
        // Load W chunk (PCB x Kn). Coalesced.
        #pragma unroll
        for (int it = 0; it < (PCB * Kn / 4) / 256; ++it) {
            int i  = tid + it * 256;
            int cc = i >> 5;              // Kn/4 = 32 float4 per row
            int c4 = (i & 31) << 2;
            *(float4*)&wsm[cc][c4] = *(const float4*)(W + (size_t)(c0 + cc) * Kn + c4);
        }
        __syncthreads();
        #pragma unroll 4
        for (int cc = 0; cc < PCB; ++cc) {
            float4 xa = *(float4*)&xs[cc][rg * 8];
            float4 xb = *(float4*)&xs[cc][rg * 8 + 4];
            float4 wa = *(float4*)&wsm[cc][cg * 8];
            float4 wb = *(float4*)&wsm[cc][cg * 8 + 4];
            float xr[8] = {xa.x, xa.y, xa.z, xa.w, xb.x, xb.y, xb.z, xb.w};
            float wr[8] = {wa.x, wa.y, wa.z, wa.w, wb.x, wb.y, wb.z, wb.w};
            #pragma unroll
            for (int i = 0; i < 8; ++i)
                #pragma unroll
                for (int j = 0; j < 8; ++j)
                    acc[i][j] = fmaf(xr[i], wr[j], acc[i][j]);
        }
    }
    // Store 8x8 tile, float4 x2 per row.
    #pragma unroll
    for (int i = 0; i < 8; ++i) {
        float4 o0 = {acc[i][0], acc[i][1], acc[i][2], acc[i][3]};
        float4 o1 = {acc[i][4], acc[i][5], acc[i][6], acc[i][7]};
        float* dst = outp + (size_t)(row0 + rg * 8 + i) * Kn + cg * 8;
        *(float4*)dst       = o0;
        *(float4*)(dst + 4) = o1;
    }
}

// ---------------------------------------------------------------------------
// Flash-style causal attention.
// Block: 256 threads handles QB=32 query rows for one batch; loops over
// SB=32 key tiles with online softmax. Only the diagonal tile is masked.
// ---------------------------------------------------------------------------
constexpr int QB = 32;
constexpr int SB = 32;

__global__ __launch_bounds__(256)
void attn_kernel(const float* __restrict__ q, const float* __restrict__ k,
                 const float* __restrict__ v, float* __restrict__ out)
{
    const int b    = blockIdx.y;
    const int qt   = blockIdx.x;
    const int row0 = qt * QB;
    const float* qb = q + ((size_t)b * Tn + row0) * Kn;
    const float* kb = k + (size_t)b * Tn * Kn;
    const float* vb = v + (size_t)b * Tn * Kn;
    float* ob = out + ((size_t)b * Tn + row0) * Kn;

    __shared__ float q_lds[QB][Kn + 4];
    __shared__ float k_lds[SB][Kn + 4];
    __shared__ float v_lds[SB][Kn + 4];
    __shared__ float s_lds[QB][SB + 4];

    const int tid = threadIdx.x;

    // Stage q tile once.
    for (int i = tid; i < QB * Kn / 4; i += 256) {
        int r = i >> 5, c4 = (i & 31) << 2;
        *(float4*)&q_lds[r][c4] = *(const float4*)(qb + (size_t)r * Kn + c4);
    }

    const int r2 = 2 * (tid >> 4);   // QK: rows r2, r2+1
    const int s2 = 2 * (tid & 15);   // QK: keys s2, s2+1
    const int sr = tid >> 3;         // softmax/PV: row
    const int sd = tid & 7;          // softmax/PV: dim group (strided by 8)

    float m_r = -INFINITY, l_r = 0.f;
    float acc[16];
    #pragma unroll
    for (int j = 0; j < 16; ++j) acc[j] = 0.f;

    const float scale = 0.08838834764831843f;  // 1/sqrt(128)

    for (int t = 0; t <= qt; ++t) {
        const int s0 = t * SB;
        __syncthreads();   // previous PV done before overwriting k/v
        for (int i = tid; i < SB * Kn / 4; i += 256) {
            int s = i >> 5, c4 = (i & 31) << 2;
            *(float4*)&k_lds[s][c4] = *(const float4*)(kb + (size_t)(s0 + s) * Kn + c4);
            *(float4*)&v_lds[s][c4] = *(const float4*)(vb + (size_t)(s0 + s) * Kn + c4);
        }
        __syncthreads();

        // QK^T: 2x2 scores per thread.
        float a00 = 0.f, a01 = 0.f, a10 = 0.f, a11 = 0.f;
        for (int cc = 0; cc < Kn; cc += 4) {
            float4 q0 = *(float4*)&q_lds[r2][cc];
            float4 q1 = *(float4*)&q_lds[r2 + 1][cc];
            float4 k0 = *(float4*)&k_lds[s2][cc];
            float4 k1 = *(float4*)&k_lds[s2 + 1][cc];
            a00 = fmaf(q0.x, k0.x, a00); a00 = fmaf(q0.y, k0.y, a00);
            a00 = fmaf(q0.z, k0.z, a00); a00 = fmaf(q0.w, k0.w, a00);
            a01 = fmaf(q0.x, k1.x, a01); a01 = fmaf(q0.y, k1.y, a01);
            a01 = fmaf(q0.z, k1.z, a01); a01 = fmaf(q0.w, k1.w, a01);
            a10 = fmaf(q1.x, k0.x, a10); a10 = fmaf(q1.y, k0.y, a10);
            a10 = fmaf(q1.z, k0.z, a10); a10 = fmaf(q1.w, k0.w, a10);
            a11 = fmaf(q1.x, k1.x, a11); a11 = fmaf(q1.y, k1.y, a11);
            a11 = fmaf(q1.z, k1.z, a11); a11 = fmaf(q1.w, k1.w, a11);
        }
        const bool diag = (t == qt);
        s_lds[r2][s2]         = (diag && (s2     > r2    )) ? -INFINITY : a00 * scale;
        s_lds[r2][s2 + 1]     = (diag && (s2 + 1 > r2    )) ? -INFINITY : a01 * scale;
        s_lds[r2 + 1][s2]     = (diag && (s2     > r2 + 1)) ? -INFINITY : a10 * scale;
        s_lds[r2 + 1][s2 + 1] = (diag && (s2 + 1 > r2 + 1)) ? -INFINITY : a11 * scale;
        __syncthreads();

        // Online softmax: 8 threads per row, 4 scores each.
        float sv[4];
        float pm = -INFINITY;
        #pragma unroll
        for (int i2 = 0; i2 < 4; ++i2) {
            sv[i2] = s_lds[sr][sd * 4 + i2];
            pm = fmaxf(pm, sv[i2]);
        }
        pm = fmaxf(pm, __shfl_xor(pm, 1));
        pm = fmaxf(pm, __shfl_xor(pm, 2));
        pm = fmaxf(pm, __shfl_xor(pm, 4));
        float mn    = fmaxf(m_r, pm);
        float alpha = __expf(m_r - mn);   // exp(-inf)=0 on first tile
        float psum  = 0.f;
        #pragma unroll
        for (int i2 = 0; i2 < 4; ++i2) {
            float p = __expf(sv[i2] - mn);
            psum += p;
            s_lds[sr][sd * 4 + i2] = p;
        }
        psum += __shfl_xor(psum, 1);
        psum += __shfl_xor(psum, 2);
        psum += __shfl_xor(psum, 4);
        l_r = l_r * alpha + psum;
        m_r = mn;
        #pragma unroll
        for (int j = 0; j < 16; ++j) acc[j] *= alpha;

        // PV: row sr's p values were written by this thread's own 8-lane group
        // (same wave) -> no barrier needed. v reads are 8-lane broadcasts,
        // conflict-free.
        #pragma unroll 4
        for (int s = 0; s < SB; ++s) {
            float p = s_lds[sr][s];
            #pragma unroll
            for (int j = 0; j < 16; ++j)
                acc[j] = fmaf(p, v_lds[s][sd + 8 * j], acc[j]);
        }
    }

    // Epilogue: normalize, bounce through LDS for coalesced stores.
    const float inv_l = 1.f / l_r;
    __syncthreads();
    #pragma unroll
    for (int j = 0; j < 16; ++j)
        q_lds[sr][sd + 8 * j] = acc[j] * inv_l;
    __syncthreads();
    for (int i = tid; i < QB * Kn / 4; i += 256) {
        int r = i >> 5, c4 = (i & 31) << 2;
        *(float4*)(ob + (size_t)r * Kn + c4) = *(float4*)&q_lds[r][c4];
    }
}

// ---------------------------------------------------------------------------
extern "C" void kernel_launch(void* const* d_in, const int* in_sizes, int n_in,
                              void* d_out, int out_size, void* d_ws, size_t ws_size,
                              hipStream_t stream)
{
    const float* x  = (const float*)d_in[0];
    const float* Wq = (const float*)d_in[1];
    const float* Wk = (const float*)d_in[2];
    const float* Wv = (const float*)d_in[3];
    float* out = (float*)d_out;

    const size_t btk = (size_t)Bn * Tn * Kn;   // 2,097,152 elements
    float* q = (float*)d_ws;
    float* k = q + btk;
    float* v = k + btk;

    dim3 pgrid(Bn * Tn / PR, 3);
    proj_kernel<<<pgrid, 256, 0, stream>>>(x, Wq, Wk, Wv, q, k, v);

    dim3 agrid(Tn / QB, Bn);
    attn_kernel<<<agrid, 256, 0, stream>>>(q, k, v, out);
}

// Round 2
// 119.163 us; speedup vs baseline: 5.9670x; 5.9670x over previous
//
#include <hip/hip_runtime.h>
#include <cmath>

#define Bn 8
#define Tn 2048
#define Cn 1024
#define Kn 128

typedef __attribute__((ext_vector_type(8))) short short8;
typedef __attribute__((ext_vector_type(4))) float f32x4;
typedef unsigned short u16;
typedef unsigned int u32;

#define NEGINF (-__builtin_huge_valf())

__device__ __forceinline__ u16 f2b(float f) {
    u32 u = __float_as_uint(f);
    u32 r = (u + 0x7FFFu + ((u >> 16) & 1u)) >> 16;
    return (u16)r;
}

__device__ __forceinline__ void load_lds16(const u16* g, u16* l) {
    __builtin_amdgcn_global_load_lds(
        (const __attribute__((address_space(1))) u32*)(g),
        (__attribute__((address_space(3))) u32*)(l), 16, 0, 0);
}

// ---------------------------------------------------------------------------
// prep: W [1024 c][128 n] fp32 -> W^T bf16 [3][128 n][1024 c]
// ---------------------------------------------------------------------------
__global__ __launch_bounds__(256)
void prep_kernel(const float* __restrict__ Wq, const float* __restrict__ Wk,
                 const float* __restrict__ Wv, u16* __restrict__ Wt)
{
    int id = blockIdx.x * 256 + threadIdx.x;      // 0 .. 98303
    int w   = id >> 15;
    int rem = id & 32767;
    int c   = rem >> 5;
    int n4  = (rem & 31) << 2;
    const float* W = (w == 0) ? Wq : (w == 1) ? Wk : Wv;
    float4 v = *(const float4*)(W + (size_t)c * Kn + n4);
    u16* dst = Wt + (size_t)w * Kn * Cn;
    dst[(size_t)(n4 + 0) * Cn + c] = f2b(v.x);
    dst[(size_t)(n4 + 1) * Cn + c] = f2b(v.y);
    dst[(size_t)(n4 + 2) * Cn + c] = f2b(v.z);
    dst[(size_t)(n4 + 3) * Cn + c] = f2b(v.w);
}

// ---------------------------------------------------------------------------
// proj: qkv[w] = x @ W[w], bf16 MFMA. 128x128 tile, 4 waves of 64x64, BK=64.
// ---------------------------------------------------------------------------
__global__ __launch_bounds__(256)
void proj_kernel(const float* __restrict__ x, const u16* __restrict__ Wt,
                 u16* __restrict__ qkv)
{
    const int w = blockIdx.y;
    const u16* wtg = Wt + (size_t)w * Kn * Cn;        // [128 n][1024 c]
    u16* outp = qkv + (size_t)w * Bn * Tn * Kn;
    const int row0 = blockIdx.x * 128;
    const int tid  = threadIdx.x;
    const int lane = tid & 63;
    const int wid  = tid >> 6;
    const int l15  = lane & 15, lh = lane >> 4;
    const int wm0 = (wid >> 1) * 64, wn0 = (wid & 1) * 64;

    __shared__ u16 xs[128][72];
    __shared__ u16 wt[128][72];

    f32x4 acc[4][4];
    #pragma unroll
    for (int i = 0; i < 4; ++i)
        #pragma unroll
        for (int j = 0; j < 4; ++j) acc[i][j] = (f32x4){0.f, 0.f, 0.f, 0.f};

    for (int kk = 0; kk < Cn; kk += 64) {
        __syncthreads();
        // stage x (128 x 64 fp32 -> bf16), rows of 16 float4
        #pragma unroll
        for (int i = 0; i < 8; ++i) {
            int idx = tid + i * 256;
            int r = idx >> 4, c4 = (idx & 15) << 2;
            float4 xv = *(const float4*)(x + (size_t)(row0 + r) * Cn + kk + c4);
            ushort4 pk = { f2b(xv.x), f2b(xv.y), f2b(xv.z), f2b(xv.w) };
            *(ushort4*)&xs[r][c4] = pk;
        }
        // stage W^T (128 n x 64 c bf16)
        #pragma unroll
        for (int i = 0; i < 4; ++i) {
            int idx = tid + i * 256;
            int n = idx >> 3, c8 = (idx & 7) << 3;
            uint4 wv = *(const uint4*)(wtg + (size_t)n * Cn + kk + c8);
            *(uint4*)&wt[n][c8] = wv;
        }
        __syncthreads();
        #pragma unroll
        for (int kc = 0; kc < 2; ++kc) {
            const int coff = kc * 32 + lh * 8;
            short8 af[4], bf[4];
            #pragma unroll
            for (int mg = 0; mg < 4; ++mg)
                af[mg] = *(const short8*)&xs[wm0 + mg * 16 + l15][coff];
            #pragma unroll
            for (int ng = 0; ng < 4; ++ng)
                bf[ng] = *(const short8*)&wt[wn0 + ng * 16 + l15][coff];
            #pragma unroll
            for (int mg = 0; mg < 4; ++mg)
                #pragma unroll
                for (int ng = 0; ng < 4; ++ng)
                    acc[mg][ng] = __builtin_amdgcn_mfma_f32_16x16x32_bf16(
                        af[mg], bf[ng], acc[mg][ng], 0, 0, 0);
        }
    }
    #pragma unroll
    for (int mg = 0; mg < 4; ++mg)
        #pragma unroll
        for (int ng = 0; ng < 4; ++ng)
            #pragma unroll
            for (int r = 0; r < 4; ++r) {
                int m = row0 + wm0 + mg * 16 + lh * 4 + r;
                int n = wn0 + ng * 16 + l15;
                outp[(size_t)m * Kn + n] = f2b(acc[mg][ng][r]);
            }
}

// ---------------------------------------------------------------------------
// attn: flash causal, QB=32 q rows / block; 4 waves = (2 s-tiles x 2 q-halves).
// S^T = K·Q^T (q is lane-local col), O^T = V^T·P^T. Blocks paired qt<->63-qt.
// LDS: K [64][128] chunk-swizzled, V^T [128][64] chunk-swizzled,
//      per-wave P [16][40], merge scratch. 39 KB total.
// ---------------------------------------------------------------------------
__global__ __launch_bounds__(256)
void attn_kernel(const u16* __restrict__ qg_, const u16* __restrict__ kg_,
                 const u16* __restrict__ vg_, float* __restrict__ out)
{
    const int bx   = blockIdx.x;
    const int half = bx >> 8, rr_ = bx & 255;
    const int b    = rr_ >> 5, jj = rr_ & 31;
    const int qt   = half ? (63 - jj) : jj;       // blocks i and i+256 pair to 65 units
    const int q0   = qt * 32;

    const u16* qw = qg_ + (size_t)b * Tn * Kn;
    const u16* kw = kg_ + (size_t)b * Tn * Kn;
    const u16* vw = vg_ + (size_t)b * Tn * Kn;

    const int tid  = threadIdx.x;
    const int lane = tid & 63;
    const int wv   = tid >> 6;
    const int l15  = lane & 15, lh = lane >> 4;
    const int qgown = wv & 1;                     // which 16-q half this wave owns

    __shared__ __align__(16) char smem[39040];
    u16*   K_lds = (u16*)smem;                    // [64][128] (chunk-swizzled rows)
    u16*   Vt    = (u16*)(smem + 16384);          // [128 d][64 s] (chunk-swizzled)
    u16*   Pw    = (u16*)(smem + 32768) + wv * 640;  // [16][40]
    float* msc   = (float*)(smem + 37888);        // [4][32]
    float* lsc   = (float*)(smem + 38400);        // [4][32]
    float* lt    = (float*)(smem + 38912);        // [32]
    float* Om    = (float*)smem;                  // [32][132] fp32, overlays K/Vt

    // Q fragments (B-operand: lane holds Q[q=l15][c=kc*32+lh*8 ..+7])
    short8 qf[4];
    {
        const int qq = q0 + qgown * 16 + l15;
        #pragma unroll
        for (int kc = 0; kc < 4; ++kc)
            qf[kc] = *(const short8*)(qw + (size_t)qq * Kn + kc * 32 + lh * 8);
    }

    f32x4 acc[8];
    #pragma unroll
    for (int i = 0; i < 8; ++i) acc[i] = (f32x4){0.f, 0.f, 0.f, 0.f};
    float m_own = NEGINF, l_own = 0.f;

    const int nsup = (qt >> 1) + 1;               // supers of 64 s (2 tiles)
    const float scale = 0.08838834764831843f;     // 1/sqrt(128)

    for (int su = 0; su < nsup; ++su) {
        const int sbase = su * 64;
        __syncthreads();
        // --- stage K [64 s][128 c] via global_load_lds, source pre-swizzled ---
        #pragma unroll
        for (int i = 0; i < 4; ++i) {
            int seg  = wv * 4 + i;                // 16 segs of 1KB
            int row  = seg * 4 + lh;              // 0..63
            int chnk = l15 ^ (row & 7);
            load_lds16(kw + (size_t)(sbase + row) * Kn + chnk * 8,
                       K_lds + seg * 512);
        }
        // --- stage V^T [128 d][64 s], reg-staged transpose, chunk-swizzled ---
        {
            int s4 = tid & 15;                    // lanes vary s fast
            int dc = tid >> 4;                    // 0..15 (8 d each)
            int s  = s4 * 4;
            u16 t4[4][8];
            #pragma unroll
            for (int r2 = 0; r2 < 4; ++r2)
                *(uint4*)t4[r2] = *(const uint4*)(vw + (size_t)(sbase + s + r2) * Kn + dc * 8);
            #pragma unroll
            for (int j = 0; j < 8; ++j) {
                int d = dc * 8 + j;
                int chnk = (s >> 3) ^ (d & 7);
                ushort4 pk = { t4[0][j], t4[1][j], t4[2][j], t4[3][j] };
                *(ushort4*)(Vt + d * 64 + chnk * 8 + (s & 7)) = pk;
            }
        }
        __syncthreads();

        const int st = su * 2 + (wv >> 1);
        if (st <= qt) {
            const int soff = (wv >> 1) * 32;      // s offset inside super
            // --- QK^T: S^T frags [s][q], accumulate over K=128 ---
            f32x4 sf0 = (f32x4){0.f,0.f,0.f,0.f}, sf1 = sf0;
            const int sw = (soff + l15) & 7;      // same for both sg halves
            #pragma unroll
            for (int kc = 0; kc < 4; ++kc) {
                int ch = (kc * 4 + lh) ^ sw;
                short8 a0 = *(const short8*)(K_lds + (soff + l15) * 128 + ch * 8);
                short8 a1 = *(const short8*)(K_lds + (soff + 16 + l15) * 128 + ch * 8);
                sf0 = __builtin_amdgcn_mfma_f32_16x16x32_bf16(a0, qf[kc], sf0, 0,0,0);
                sf1 = __builtin_amdgcn_mfma_f32_16x16x32_bf16(a1, qf[kc], sf1, 0,0,0);
            }
            // --- mask + online softmax (q = lane-local col) ---
            const int q_g = q0 + qgown * 16 + l15;
            float pvv[8];
            float pmax = NEGINF;
            #pragma unroll
            for (int r = 0; r < 4; ++r) {
                int s0g = st * 32 + lh * 4 + r;
                float v0 = sf0[r] * scale; if (s0g > q_g) v0 = NEGINF;
                float v1 = sf1[r] * scale; if (s0g + 16 > q_g) v1 = NEGINF;
                pvv[r] = v0; pvv[4 + r] = v1;
                pmax = fmaxf(pmax, fmaxf(v0, v1));
            }
            pmax = fmaxf(pmax, __shfl_xor(pmax, 16));
            pmax = fmaxf(pmax, __shfl_xor(pmax, 32));
            float mn = fmaxf(m_own, pmax);
            float alpha = __expf(m_own - mn);
            m_own = mn;
            float ps = 0.f;
            #pragma unroll
            for (int i2 = 0; i2 < 8; ++i2) { pvv[i2] = __expf(pvv[i2] - mn); ps += pvv[i2]; }
            ps += __shfl_xor(ps, 16);
            ps += __shfl_xor(ps, 32);
            l_own = l_own * alpha + ps;
            // --- P -> LDS (bf16), wave-local ---
            ushort4 pk0 = { f2b(pvv[0]), f2b(pvv[1]), f2b(pvv[2]), f2b(pvv[3]) };
            ushort4 pk1 = { f2b(pvv[4]), f2b(pvv[5]), f2b(pvv[6]), f2b(pvv[7]) };
            *(ushort4*)(Pw + l15 * 40 + lh * 4)      = pk0;
            *(ushort4*)(Pw + l15 * 40 + 16 + lh * 4) = pk1;
            // --- rescale + PV: O^T += V^T · P^T ---
            #pragma unroll
            for (int dg = 0; dg < 8; ++dg) acc[dg] *= alpha;
            short8 pf = *(const short8*)(Pw + l15 * 40 + lh * 8);
            #pragma unroll
            for (int dg = 0; dg < 8; ++dg) {
                int d = dg * 16 + l15;
                int ch = ((soff >> 3) + lh) ^ (d & 7);
                short8 a = *(const short8*)(Vt + d * 64 + ch * 8);
                acc[dg] = __builtin_amdgcn_mfma_f32_16x16x32_bf16(a, pf, acc[dg], 0,0,0);
            }
        }
    }

    // --- merge 4 waves' partials ---
    __syncthreads();
    for (int i = tid; i < 32 * 132; i += 256) Om[i] = 0.f;
    msc[wv * 32 + qgown * 16 + l15]       = m_own;
    msc[wv * 32 + (1 ^ qgown) * 16 + l15] = NEGINF;
    lsc[wv * 32 + qgown * 16 + l15]       = l_own;
    lsc[wv * 32 + (1 ^ qgown) * 16 + l15] = 0.f;
    __syncthreads();
    float f_own = 0.f;
    #pragma unroll
    for (int qg = 0; qg < 2; ++qg) {
        int qq = qg * 16 + l15;
        float ms = fmaxf(fmaxf(msc[qq], msc[32 + qq]),
                         fmaxf(msc[64 + qq], msc[96 + qq]));
        float ltot = 0.f;
        #pragma unroll
        for (int w2 = 0; w2 < 4; ++w2)
            ltot += lsc[w2 * 32 + qq] * __expf(msc[w2 * 32 + qq] - ms);
        lt[qq] = ltot;
        if (qg == qgown) f_own = __expf(m_own - ms);
    }
    #pragma unroll
    for (int dg = 0; dg < 8; ++dg)
        #pragma unroll
        for (int r = 0; r < 4; ++r) {
            int d  = dg * 16 + lh * 4 + r;
            int qq = qgown * 16 + l15;
            atomicAdd(&Om[qq * 132 + d], acc[dg][r] * f_own);
        }
    __syncthreads();
    #pragma unroll
    for (int i = 0; i < 4; ++i) {
        int idx = tid + i * 256;
        int qq = idx >> 5, d4 = (idx & 31) << 2;
        float inv = 1.f / lt[qq];
        float4 o;
        o.x = Om[qq * 132 + d4 + 0] * inv;
        o.y = Om[qq * 132 + d4 + 1] * inv;
        o.z = Om[qq * 132 + d4 + 2] * inv;
        o.w = Om[qq * 132 + d4 + 3] * inv;
        *(float4*)(out + ((size_t)b * Tn + q0 + qq) * Kn + d4) = o;
    }
}

// ---------------------------------------------------------------------------
extern "C" void kernel_launch(void* const* d_in, const int* in_sizes, int n_in,
                              void* d_out, int out_size, void* d_ws, size_t ws_size,
                              hipStream_t stream)
{
    const float* x  = (const float*)d_in[0];
    const float* Wq = (const float*)d_in[1];
    const float* Wk = (const float*)d_in[2];
    const float* Wv = (const float*)d_in[3];
    float* out = (float*)d_out;

    u16* ws = (u16*)d_ws;
    const size_t btk = (size_t)Bn * Tn * Kn;       // 2,097,152
    u16* q  = ws;
    u16* k  = ws + btk;
    u16* v  = ws + 2 * btk;
    u16* Wt = ws + 3 * btk;                        // 3 x 128 x 1024 bf16

    prep_kernel<<<384, 256, 0, stream>>>(Wq, Wk, Wv, Wt);
    proj_kernel<<<dim3(128, 3), 256, 0, stream>>>(x, Wt, ws);
    attn_kernel<<<512, 256, 0, stream>>>(q, k, v, out);
}